// Round 1
// 112.097 us; speedup vs baseline: 1.1190x; 1.1190x over previous
//
#include <hip/hip_runtime.h>
#include <stdint.h>

#define BB 16
#define CC 4
#define HH 512
#define WW 512
#define NWORDS 8          // 512 / 64
#define HW (HH * WW)

// ---------------- ws layout ----------------
// [1024]   : unsigned flags32[B][H] — per-row, 4-bit nibble per class:
//            bit0 anyT, bit1 any p==1, bit2 any p==0, bit3 any p!=0   (32 KB)
// [256K]   : u64 tgt_bits [C][B][H][NWORDS]   2 MiB
// [+2MB]   : u64 ppos_bits[C][B][H][NWORDS]  (p==1.0)
// [+4MB]   : u64 pneg_bits[C][B][H][NWORDS]  (p==0.0)
#define OFF_ROW   1024
#define OFF_TGT   262144
#define BOARD_BYTES (CC * BB * HH * NWORDS * 8)   // 2 MiB

// build_bits v2: 4 px/thread, float4/int4 loads (16 B/lane).
// Screen: p==0.0f / p==1.0f require logit spread >= ln(2^25/4) ~ 15.9
// (s <= 4*e_max  =>  1-p >= e^-spread/4 > 2^-25 and p >= e^-spread/4 > 0),
// so spread < 15.0 proves all flags are 0 without computing softmax.
// Block = 512 thr = 4 rows; wave = half row. Grid = B*H/4 = 2048.
__launch_bounds__(512)
__global__ void build_bits(const int* __restrict__ tgt,
                           const float* __restrict__ pred,
                           uint64_t* __restrict__ tgtb,
                           uint64_t* __restrict__ ppos,
                           uint64_t* __restrict__ pneg,
                           unsigned* __restrict__ flags32,
                           float* __restrict__ out) {
    __shared__ unsigned sfl[4][2];
    int t = threadIdx.x;
    int r = t >> 7;                 // row within block (0..3)
    int j = t & 127;                // 16B chunk within row (x0 = 4j)
    int row = blockIdx.x * 4 + r;   // 0..B*H-1
    int b = row >> 9, y = row & (HH - 1);
    if (blockIdx.x == 0 && t == 0) out[0] = 0.0f;

    const int4* tg4 = reinterpret_cast<const int4*>(tgt);
    int4 tv = tg4[(size_t)row * 128 + j];

    float pa[4][4];                 // [class][px] — all indices compile-time
    const float4* pr4 = reinterpret_cast<const float4*>(pred);
#pragma unroll
    for (int c = 0; c < 4; ++c) {
        float4 v = pr4[((size_t)(b * 4 + c) * HH + y) * 128 + j];
        pa[c][0] = v.x; pa[c][1] = v.y; pa[c][2] = v.z; pa[c][3] = v.w;
    }

    bool anyhard = false;
#pragma unroll
    for (int k = 0; k < 4; ++k) {
        float mx = fmaxf(fmaxf(pa[0][k], pa[1][k]), fmaxf(pa[2][k], pa[3][k]));
        float mn = fminf(fminf(pa[0][k], pa[1][k]), fminf(pa[2][k], pa[3][k]));
        anyhard |= (mx - mn >= 15.0f);
    }
    uint64_t hard = __ballot(anyhard);   // wave-uniform branch selector

    unsigned tn[4], ppn[4] = {0u, 0u, 0u, 0u}, pnn[4] = {0u, 0u, 0u, 0u};
#pragma unroll
    for (int c = 0; c < 4; ++c)
        tn[c] = (unsigned)(tv.x == c) | ((unsigned)(tv.y == c) << 1)
              | ((unsigned)(tv.z == c) << 2) | ((unsigned)(tv.w == c) << 3);

    if (hard) {   // cold: exact softmax (mirrors reference rounding: e/s divide)
#pragma unroll
        for (int k = 0; k < 4; ++k) {
            float mx = fmaxf(fmaxf(pa[0][k], pa[1][k]), fmaxf(pa[2][k], pa[3][k]));
            float e[4], s = 0.f;
#pragma unroll
            for (int c = 0; c < 4; ++c) { e[c] = expf(pa[c][k] - mx); s += e[c]; }
#pragma unroll
            for (int c = 0; c < 4; ++c) {
                float p = e[c] / s;
                ppn[c] |= (unsigned)(p == 1.0f) << k;
                pnn[c] |= (unsigned)(p == 0.0f) << k;
            }
        }
    }

    // per-thread flag nibbles, OR-reduced across the wave (= half row)
    unsigned fl = 0u;
#pragma unroll
    for (int c = 0; c < 4; ++c) {
        unsigned f = (tn[c] ? 1u : 0u) | (ppn[c] ? 2u : 0u) | (pnn[c] ? 4u : 0u)
                   | ((pnn[c] != 0xFu) ? 8u : 0u);
        fl |= f << (4 * c);
    }
#pragma unroll
    for (int o = 1; o < 64; o <<= 1) fl |= __shfl_xor(fl, o, 64);
    if ((t & 63) == 0) sfl[r][(t >> 6) & 1] = fl;

    // assemble u16 bit-words (2-step shfl nibble pack) and store
    unsigned short* t16 = reinterpret_cast<unsigned short*>(tgtb);
    unsigned short* p16 = reinterpret_cast<unsigned short*>(ppos);
    unsigned short* n16 = reinterpret_cast<unsigned short*>(pneg);
#pragma unroll
    for (int c = 0; c < 4; ++c) {
        size_t base16 = ((size_t)(c * BB + b) * HH + y) * (NWORDS * 4);
        unsigned v = tn[c];
        v |= __shfl_down(v, 1, 64) << 4;
        v |= __shfl_down(v, 2, 64) << 8;
        if ((j & 3) == 0) t16[base16 + (j >> 2)] = (unsigned short)v;
        if (hard) {
            unsigned vp = ppn[c];
            vp |= __shfl_down(vp, 1, 64) << 4;
            vp |= __shfl_down(vp, 2, 64) << 8;
            unsigned vn = pnn[c];
            vn |= __shfl_down(vn, 1, 64) << 4;
            vn |= __shfl_down(vn, 2, 64) << 8;
            if ((j & 3) == 0) {
                p16[base16 + (j >> 2)] = (unsigned short)vp;
                n16[base16 + (j >> 2)] = (unsigned short)vn;
            }
        } else if ((j & 15) == 0) {   // common: boards are all-zero
            size_t wbase = ((size_t)(c * BB + b) * HH + y) * NWORDS + (j >> 4);
            ppos[wbase] = 0ull;
            pneg[wbase] = 0ull;
        }
    }
    __syncthreads();
    if (t < 4) {
        int rr = blockIdx.x * 4 + t;
        flags32[rr] = sfl[t][0] | sfl[t][1];
    }
}

// ---------- general per-pixel helpers (cold fallback path) ----------
__device__ __forceinline__ unsigned win11(const uint64_t* row10, int idx, int p) {
    uint64_t w;
    if (p < 64) {
        w = (row10[idx] >> p) | (row10[idx + 1] << (64 - p));
    } else {
        int q = p - 64;
        uint64_t M = row10[idx + 1];
        w = q ? ((M >> q) | (row10[idx + 2] << (64 - q))) : M;
    }
    return (unsigned)w & 0x7FFu;
}

__device__ __forceinline__ void upd(int& mind2, unsigned wbits, int dy2) {
    if (wbits) {
        unsigned hi = wbits >> 5;
        unsigned lo = wbits & 31u;
        int mdx = 6;
        if (hi) mdx = __ffs(hi) - 1;
        if (lo) {
            int m2 = 5 - (31 - __clz(lo));
            mdx = min(mdx, m2);
        }
        int cand = dy2 + mdx * mdx;
        mind2 = min(mind2, cand);
    }
}

// Fast-path row macros: ALL DT/DC indices are literals — guaranteed SROA to
// registers regardless of unroll decisions (rule #20 defense). d2==25 levels
// are dropped (dist 5 == cap, folded into the ~cov term) => dy range is ±4.
#define SSTEP(S, LI)                                                          \
    UT |= (Cw >> (S)) | (Rw << (64 - (S))) | (Cw << (S)) | (Lw >> (64 - (S)));\
    UC |= (Cc >> (S)) | (Rc << (64 - (S))) | (Cc << (S)) | (Lc >> (64 - (S)));\
    DT[LI] |= UT; DC[LI] |= UC;

#define PROW(DY, MAXS, LI0, LI1, LI2, LI3, LI4)                               \
    do {                                                                      \
        int yy = y + (DY);                                                    \
        if (yy >= 0 && yy < HH) {                                             \
            const int ly = tr + 4 + (DY);                                     \
            uint64_t Cw = sT[ly][w];                                          \
            uint64_t Lw = (w > 0) ? sT[ly][w - 1] : 0ull;                     \
            uint64_t Rw = (w < 7) ? sT[ly][w + 1] : 0ull;                     \
            uint64_t Cc = ~Cw;                                                \
            uint64_t Lc = (w > 0) ? ~Lw : 0ull;                               \
            uint64_t Rc = (w < 7) ? ~Rw : 0ull;                               \
            uint64_t UT = Cw, UC = Cc;                                        \
            DT[LI0] |= UT; DC[LI0] |= UC;                                     \
            if ((MAXS) >= 1) { SSTEP(1, LI1) }                                \
            if ((MAXS) >= 2) { SSTEP(2, LI2) }                                \
            if ((MAXS) >= 3) { SSTEP(3, LI3) }                                \
            if ((MAXS) >= 4) { SSTEP(4, LI4) }                                \
        }                                                                     \
    } while (0)

// One block per (cb, 64-row tile). Fast: word-parallel level-set sum (13
// levels, d2 in {0,1,2,4,5,8,9,10,13,16,17,18,20}); else general per-pixel.
__launch_bounds__(512)
__global__ void edt_main(const uint64_t* __restrict__ tgtb,
                         const uint64_t* __restrict__ pposb,
                         const uint64_t* __restrict__ pnegb,
                         const unsigned* __restrict__ flags32,
                         float* __restrict__ out) {
    __shared__ uint64_t shm[72 * 8];     // fast: sT[72][8]; general: sh[3][11][10]
    __shared__ float wsum[8];
    __shared__ unsigned sflag[8];
    int tile = blockIdx.x & 7;
    int cb   = blockIdx.x >> 3;
    int y0   = tile * 64;
    int b = cb & (BB - 1);
    int c = cb >> 4;
    const float INV_N = 1.0f / 16777216.0f;   // 1/(B*H*W*C)

    // ---- derive (c,b) flags from per-row nibbles ----
    {
        unsigned rs = (flags32[(size_t)b * HH + threadIdx.x] >> (4 * c)) & 0xFu;
        uint64_t bT = __ballot((rs & 1u) != 0u);
        uint64_t bP = __ballot((rs & 2u) != 0u);
        uint64_t bN = __ballot((rs & 4u) != 0u);
        uint64_t bZ = __ballot((rs & 8u) != 0u);   // rows with some p!=0
        if ((threadIdx.x & 63) == 0)
            sflag[threadIdx.x >> 6] = (bT ? 1u : 0u) | (bP ? 2u : 0u)
                                    | (bN ? 4u : 0u) | (bZ ? 8u : 0u);
        __syncthreads();
        if (threadIdx.x == 0) {
            unsigned o = 0u;
#pragma unroll
            for (int i = 0; i < 8; ++i) o |= sflag[i];
            sflag[0] = o;
        }
        __syncthreads();
    }
    unsigned F = sflag[0];
    bool present  = (F & 1u) != 0u;
    bool anyppos  = (F & 2u) != 0u;
    bool anypneg  = (F & 4u) != 0u;
    bool prednz   = (F & 8u) != 0u;
    bool fast     = !anyppos && !anypneg;   // psdf == 0 uniformly

    if (fast) {
        if (!present) {
            if (tile == 0 && threadIdx.x == 0)
                atomicAdd(out, 3.0f * (float)HW * INV_N);
            return;
        }
        uint64_t (*sT)[8] = (uint64_t (*)[8])shm;
        const uint64_t* board = tgtb + (size_t)cb * HH * NWORDS;
        for (int tt = threadIdx.x; tt < 72 * 8; tt += 512) {
            int rr = tt >> 3, ww = tt & 7;
            int yy = y0 + rr - 4;
            sT[rr][ww] = (yy >= 0 && yy < HH) ? board[(size_t)yy * NWORDS + ww] : 0ull;
        }
        __syncthreads();

        int tr = threadIdx.x >> 3;    // row within tile (0..63)
        int w  = threadIdx.x & 7;     // word column (0..7)
        int y  = y0 + tr;

        uint64_t DT[13], DC[13];
#pragma unroll
        for (int k = 0; k < 13; ++k) { DT[k] = 0ull; DC[k] = 0ull; }

        //        DY MAXS  s=0  s=1  s=2  s=3  s=4      (level index table)
        PROW(-4, 2,   9,  10,  12,   0,   0);
        PROW(-3, 3,   6,   7,   8,  11,   0);
        PROW(-2, 4,   3,   4,   5,   8,  12);
        PROW(-1, 4,   1,   2,   4,   7,  10);
        PROW( 0, 4,   0,   1,   3,   6,   9);
        PROW( 1, 4,   1,   2,   4,   7,  10);
        PROW( 2, 4,   3,   4,   5,   8,  12);
        PROW( 3, 3,   6,   7,   8,  11,   0);
        PROW( 4, 2,   9,  10,  12,   0,   0);

        const float dist13[13] = {0.f, 1.f, 1.41421356f, 2.f, 2.23606798f,
            2.82842712f, 3.f, 3.16227766f, 3.60555128f, 4.f, 4.12310563f,
            4.24264069f, 4.47213595f};
        uint64_t covT = DT[0], covC = DC[0];
        float s = 0.f;
#pragma unroll
        for (int k = 1; k < 13; ++k) {
            uint64_t nT = DT[k] & ~covT;
            uint64_t nC = DC[k] & ~covC;
            s += dist13[k] * (float)(__popcll(nT) + __popcll(nC));
            covT |= DT[k];
            covC |= DC[k];
        }
        s += 5.f * (float)(__popcll(~covT) + __popcll(~covC));

        for (int o = 32; o > 0; o >>= 1) s += __shfl_down(s, o, 64);
        if ((threadIdx.x & 63) == 0) wsum[threadIdx.x >> 6] = s;
        __syncthreads();
        if (threadIdx.x == 0) {
            float tot = 0.f;
#pragma unroll
            for (int i = 0; i < 8; ++i) tot += wsum[i];
            atomicAdd(out, tot * 0.2f * INV_N);   // /5 and normalize
        }
        return;
    }

    // ---------- general path (cold): per-pixel over 64 rows ----------
    uint64_t (*sh)[11][10] = (uint64_t (*)[11][10])shm;
    int x = threadIdx.x;
    int idx = x >> 6, off = x & 63, p = off + 59;

    unsigned vmask = 0x7FFu;
    if (x < 5) vmask &= (0x7FFu << (5 - x)) & 0x7FFu;
    if (x > WW - 6) vmask &= 0x7FFu >> (x - (WW - 6));

    float vsum = 0.f;
    for (int yy = 0; yy < 64; ++yy) {
        int y = y0 + yy;
        __syncthreads();     // previous iteration's reads complete
        for (int tt = threadIdx.x; tt < 330; tt += 512) {
            int m = tt / 110;
            int rem = tt - m * 110;
            int rr = rem / 10;
            int wi = rem - rr * 10;
            int rowy = y + rr - 5;
            uint64_t v = 0;
            if (wi >= 1 && wi <= 8 && rowy >= 0 && rowy < HH) {
                const uint64_t* src = (m == 0) ? tgtb : (m == 1) ? pposb : pnegb;
                v = src[(((size_t)c * BB + b) * HH + rowy) * NWORDS + (wi - 1)];
            }
            sh[m][rr][wi] = v;
        }
        __syncthreads();

        int tp = 26, tn = 26, qp = 26, qn = 26;
#pragma unroll
        for (int dy = -5; dy <= 5; ++dy) {
            int ady = dy < 0 ? -dy : dy;
            unsigned allowed = (ady == 0) ? 0x7FFu
                             : (ady <= 3) ? 0x3FEu
                             : (ady == 4) ? 0x1FCu
                                          : 0x020u;
            int dy2 = dy * dy;
            int rr = dy + 5;
            unsigned wt  = win11(&sh[0][rr][0], idx, p);
            unsigned wpp = win11(&sh[1][rr][0], idx, p);
            unsigned wpn = win11(&sh[2][rr][0], idx, p);
            upd(tp, wt & allowed, dy2);
            upd(tn, (~wt) & vmask & allowed, dy2);
            upd(qp, wpp & allowed, dy2);
            upd(qn, wpn & allowed, dy2);
        }

        float dtp = (tp <= 25) ? sqrtf((float)tp) : 5.0f;
        float dtn = (tn <= 25) ? sqrtf((float)tn) : 5.0f;
        float dqp = (qp <= 25) ? sqrtf((float)qp) : 5.0f;
        float dqn = (qn <= 25) ? sqrtf((float)qn) : 5.0f;

        float td = fminf(fmaxf(dtp - dtn, -5.0f), 5.0f) / 5.0f;
        float qd = fminf(fmaxf(dqp - dqn, -5.0f), 5.0f) / 5.0f;
        float tsdf = present ? td : 3.0f;
        float psdf = prednz ? qd : 3.0f;
        vsum += fabsf(psdf - tsdf);
    }

    for (int o2 = 32; o2 > 0; o2 >>= 1) vsum += __shfl_down(vsum, o2, 64);
    if (off == 0) wsum[idx] = vsum;
    __syncthreads();
    if (threadIdx.x == 0) {
        float stot = 0.f;
#pragma unroll
        for (int i = 0; i < 8; ++i) stot += wsum[i];
        atomicAdd(out, stot * INV_N);
    }
}

extern "C" void kernel_launch(void* const* d_in, const int* in_sizes, int n_in,
                              void* d_out, int out_size, void* d_ws, size_t ws_size,
                              hipStream_t stream) {
    const float* pred  = (const float*)d_in[0];
    const int* target  = (const int*)d_in[1];
    float* out = (float*)d_out;

    char* ws = (char*)d_ws;
    unsigned* flags32 = (unsigned*)(ws + OFF_ROW);
    uint64_t* tgtb    = (uint64_t*)(ws + OFF_TGT);
    uint64_t* pposb   = (uint64_t*)(ws + OFF_TGT + (size_t)BOARD_BYTES);
    uint64_t* pnegb   = (uint64_t*)(ws + OFF_TGT + 2 * (size_t)BOARD_BYTES);

    hipLaunchKernelGGL(build_bits, dim3(BB * HH / 4), dim3(512), 0, stream,
                       target, pred, tgtb, pposb, pnegb, flags32, out);
    hipLaunchKernelGGL(edt_main, dim3(CC * BB * 8), dim3(512), 0, stream,
                       tgtb, pposb, pnegb, flags32, out);
}